// Round 9
// baseline (515.594 us; speedup 1.0000x reference)
//
#include <hip/hip_runtime.h>
#include <hip/hip_bf16.h>

#define NN 50000
#define NE 800000
#define NG 256
#define DIN 128
#define DH 512
#define DC 256   // conv channels
#define DL 128   // lin2 out
#define NB 49    // scan blocks: ceil(50000/1024)
#define SLW 32   // slice width (channels); 8 slices of 32 ch, 3.2MB each

// ---------------- workspace layout (bytes) ----------------
#define XBF_OFF   0UL            // 50000*128*2  = 12,800,000
#define H1BF_OFF  12800000UL     // 50000*512*2  = 51,200,000 -> 64,000,000
#define HWBF_OFF  64000000UL     // 50000*256*2  = 25,600,000 -> 89,600,000  (slice-major)
#define H2BF_OFF  89600000UL     // 25,600,000 -> 115,200,000               (slice-major)
#define H3BF_OFF  115200000UL    // 25,600,000 -> 140,800,000               (slice-major)
#define W1T_OFF   140800000UL    // 131,072 -> 140,931,072
#define WC1T_OFF  140931072UL    // 262,144 -> 141,193,216
#define WC2T_OFF  141193216UL    // 131,072 -> 141,324,288
#define CNT_OFF   141324288UL    // 200,000
#define FILL_OFF  141524288UL    // 200,000 (must directly follow CNT: one memset)
#define DINV_OFF  141724288UL    // 200,000
#define RP_OFF    141924288UL    // 200,004
#define BSUM_OFF  142124416UL    // 256
#define EW_OFF    142124800UL    // 800000*4 = 3,200,000 -> end 145,324,800

using bf16x8 = __attribute__((ext_vector_type(8))) short;
using f32x4  = __attribute__((ext_vector_type(4))) float;

__device__ __forceinline__ short f2bf(float f) {
  unsigned u = __builtin_bit_cast(unsigned, f);
  unsigned r = u + 0x7fffu + ((u >> 16) & 1u);   // round-to-nearest-even
  return (short)(r >> 16);
}
__device__ __forceinline__ float bf2f(unsigned short u) {
  return __builtin_bit_cast(float, (unsigned)u << 16);
}

// async global->LDS, 16B per lane. LDS dest = wave-uniform base + lane*16.
__device__ __forceinline__ void gload_lds16(const void* g, void* l) {
  typedef const __attribute__((address_space(1))) unsigned gu32;
  typedef __attribute__((address_space(3))) unsigned lu32;
  __builtin_amdgcn_global_load_lds((gu32*)g, (lu32*)l, 16, 0, 0);
}

// ---------------- graph-structure kernels ----------------
__global__ void count_in(const int* __restrict__ dst, int* __restrict__ cnt) {
  int e = blockIdx.x * blockDim.x + threadIdx.x;
  if (e < NE) atomicAdd(&cnt[dst[e]], 1);
}

// ---- 3-phase exclusive scan of cnt -> rowptr; also writes dinv ----
__global__ __launch_bounds__(1024) void scan_p1(const int* __restrict__ cnt,
                                                int* __restrict__ rowptr,
                                                int* __restrict__ bsum,
                                                float* __restrict__ dinv) {
  __shared__ int wsum[16];
  const int idx = blockIdx.x * 1024 + threadIdx.x;
  const int lane = threadIdx.x & 63, wid = threadIdx.x >> 6;
  int v = (idx < NN) ? cnt[idx] : 0;
  int incl = v;
  #pragma unroll
  for (int s = 1; s < 64; s <<= 1) {
    int t = __shfl_up(incl, s, 64);
    if (lane >= s) incl += t;
  }
  if (lane == 63) wsum[wid] = incl;
  __syncthreads();
  if (wid == 0 && lane < 16) {
    int w = wsum[lane];
    int wincl = w;
    #pragma unroll
    for (int s = 1; s < 16; s <<= 1) {
      int t = __shfl_up(wincl, s, 64);
      if (lane >= s) wincl += t;
    }
    wsum[lane] = wincl - w;                 // exclusive wave offset
    if (lane == 15) bsum[blockIdx.x] = wincl;
  }
  __syncthreads();
  if (idx < NN) {
    rowptr[idx] = wsum[wid] + incl - v;
    dinv[idx] = 1.0f / sqrtf((float)(v + 1));   // +1 self-loop
  }
}

__global__ void scan_p2(int* __restrict__ bsum, int* __restrict__ rowptr) {
  const int lane = threadIdx.x;
  int v = (lane < NB) ? bsum[lane] : 0;
  int incl = v;
  #pragma unroll
  for (int s = 1; s < 64; s <<= 1) {
    int t = __shfl_up(incl, s, 64);
    if (lane >= s) incl += t;
  }
  if (lane < NB) bsum[lane] = incl - v;
  if (lane == 63) rowptr[NN] = incl;        // == NE
}

__global__ __launch_bounds__(1024) void scan_p3(int* __restrict__ rowptr,
                                                const int* __restrict__ bsum) {
  const int idx = blockIdx.x * 1024 + threadIdx.x;
  if (idx < NN && blockIdx.x > 0) rowptr[idx] += bsum[blockIdx.x];
}

// fill CSR: packed 4B edge record = src_idx (u16) | bf16(weight) << 16
__global__ void fill_csr(const int* __restrict__ src, const int* __restrict__ dst,
                         const int* __restrict__ rowptr, int* __restrict__ fill,
                         const float* __restrict__ dinv, unsigned* __restrict__ ewp) {
  int e = blockIdx.x * blockDim.x + threadIdx.x;
  if (e < NE) {
    int d = dst[e];
    int s = src[e];
    int pos = rowptr[d] + atomicAdd(&fill[d], 1);
    float w = dinv[d] * dinv[s];
    ewp[pos] = (unsigned)s | ((unsigned)(unsigned short)f2bf(w) << 16);
  }
}

// ---------------- fused prep: x->bf16 + 3 weight transposes ----------------
// ranges: [0, 800000) cvt x (8 elems each); then W1t 65536; Wc1t 131072; Wc2t 65536
__global__ void prep(const float* __restrict__ x, short* __restrict__ xbf,
                     const float* __restrict__ W1, short* __restrict__ W1t,
                     const float* __restrict__ Wc1, short* __restrict__ Wc1t,
                     const float* __restrict__ Wc2, short* __restrict__ Wc2t) {
  int idx = blockIdx.x * 256 + threadIdx.x;
  if (idx < 800000) {
    const float4* p = (const float4*)x + (long)idx * 2;
    float4 a = p[0], b = p[1];
    bf16x8 o;
    o[0] = f2bf(a.x); o[1] = f2bf(a.y); o[2] = f2bf(a.z); o[3] = f2bf(a.w);
    o[4] = f2bf(b.x); o[5] = f2bf(b.y); o[6] = f2bf(b.z); o[7] = f2bf(b.w);
    *(bf16x8*)(xbf + (long)idx * 8) = o;
  } else if (idx < 865536) {
    int j = idx - 800000;             // W1t[512][128]
    int n = j >> 7, k = j & 127;
    W1t[j] = f2bf(W1[k * DH + n]);
  } else if (idx < 996608) {
    int j = idx - 865536;             // Wc1t[256][512]
    int n = j >> 9, k = j & 511;
    Wc1t[j] = f2bf(Wc1[k * DC + n]);
  } else if (idx < 1062144) {
    int j = idx - 996608;             // Wc2t[256][256]
    int n = j >> 8, k = j & 255;
    Wc2t[j] = f2bf(Wc2[k * DC + n]);
  }
}

// ---------------- bf16 MFMA GEMM v3: optional slice-major A / C ----------------
// 128x128 tile, 4 waves (2x2), 16x16x32 MFMA, 4x4 fragments/wave, BK=32.
// A_SLICED: A stored [8][NN][32] (BK=32 step == one slice -> fully contiguous).
// C_SLICED: C written [8][NN][32].
template<int DO_RELU, int HAS_BIAS, int A_SLICED, int C_SLICED>
__global__ __launch_bounds__(256) void gemm_mfma3(
    const short* __restrict__ A, const short* __restrict__ Bt,
    const float* __restrict__ bias, short* __restrict__ Cout,
    int M, int K, int N)
{
  __shared__ __align__(16) short As[128][32];
  __shared__ __align__(16) short Bs[128][32];
  const int tid  = threadIdx.x;
  const int lane = tid & 63;
  const int wave = tid >> 6;
  const int wr   = wave >> 1;
  const int wc   = wave & 1;
  const int bm = blockIdx.y * 128;
  const int bn = blockIdx.x * 128;

  const int srow = lane >> 2;        // 0..15 within 16-row chunk
  const int scol = (lane & 3) * 8;   // short col base 0/8/16/24

  f32x4 acc[4][4];
  #pragma unroll
  for (int m = 0; m < 4; ++m)
    #pragma unroll
    for (int n = 0; n < 4; ++n)
      acc[m][n] = f32x4{0.f, 0.f, 0.f, 0.f};

  const int fr = lane & 15;
  const int kb = (lane >> 4) * 8;

  for (int k0 = 0; k0 < K; k0 += 32) {
    #pragma unroll
    for (int j = 0; j < 2; ++j) {
      const int r = wave * 32 + j * 16;
      const short* ap;
      if (A_SLICED)
        ap = A + (long)(k0 >> 5) * ((long)NN * SLW) + (long)(bm + r + srow) * SLW + scol;
      else
        ap = A + (long)(bm + r + srow) * K + k0 + scol;
      gload_lds16(ap, &As[r][0]);
      gload_lds16(Bt + (long)(bn + r + srow) * K + k0 + scol, &Bs[r][0]);
    }
    __syncthreads();
    bf16x8 af[4], bfr[4];
    #pragma unroll
    for (int m = 0; m < 4; ++m)
      af[m] = *(const bf16x8*)&As[wr * 64 + m * 16 + fr][kb];
    #pragma unroll
    for (int n = 0; n < 4; ++n)
      bfr[n] = *(const bf16x8*)&Bs[wc * 64 + n * 16 + fr][kb];
    #pragma unroll
    for (int m = 0; m < 4; ++m)
      #pragma unroll
      for (int n = 0; n < 4; ++n)
        acc[m][n] = __builtin_amdgcn_mfma_f32_16x16x32_bf16(af[m], bfr[n], acc[m][n], 0, 0, 0);
    __syncthreads();
  }

  const int cr4 = (lane >> 4) * 4;
  const int cc  = lane & 15;
  #pragma unroll
  for (int m = 0; m < 4; ++m) {
    #pragma unroll
    for (int r = 0; r < 4; ++r) {
      int gm = bm + wr * 64 + m * 16 + cr4 + r;
      if (gm >= M) continue;
      #pragma unroll
      for (int n = 0; n < 4; ++n) {
        int gn = bn + wc * 64 + n * 16 + cc;
        float v = acc[m][n][r];
        if (HAS_BIAS) v += bias[gn];
        if (DO_RELU) v = fmaxf(v, 0.f);
        long cidx = C_SLICED ? ((long)(gn >> 5) * ((long)NN * SLW) + (long)gm * SLW + (gn & 31))
                             : ((long)gm * N + gn);
        Cout[cidx] = f2bf(v);
      }
    }
  }
}

// ---------------- GCN aggregation v7: contiguous slice per XCD ----------------
// slice = blockIdx&7 (round-robin block->XCD): slice data hw[s][NN][32] is a
// CONTIGUOUS 3.2MB region -> fits one XCD's 4MB L2 with no set aliasing.
// Block = 4 waves = 4 nodes (same slice). Wave: 8 edge-groups x 8 lanes;
// lane = ushort4 (8B); one edge-gather = one 64B line. 2x unrolled (16 in flight).
// Edge records (4B) nt-loaded (read 8x across slices). 3-shfl combine.
__global__ __launch_bounds__(256) void aggregate_v7(
    const unsigned short* __restrict__ hw, const unsigned* __restrict__ ewp,
    const int* __restrict__ rowptr, const float* __restrict__ dinv,
    const float* __restrict__ bias, unsigned short* __restrict__ out)
{
  const int slice = blockIdx.x & 7;
  const int wid   = threadIdx.x >> 6;
  const int lane  = threadIdx.x & 63;
  const int i = (blockIdx.x >> 3) * 4 + wid;
  if (i >= NN) return;
  const int g = lane >> 3;                 // edge group 0..7
  const int p = lane & 7;                  // channel-lane within group
  const unsigned short* hwS = hw + (long)slice * ((long)NN * SLW) + p * 4;

  float a0 = 0.f, a1 = 0.f, a2 = 0.f, a3 = 0.f;
  const int s0 = rowptr[i], s1 = rowptr[i + 1];
  int e = s0;
  for (; e + 16 <= s1; e += 16) {
    unsigned pk0 = __builtin_nontemporal_load(ewp + e + g);
    unsigned pk1 = __builtin_nontemporal_load(ewp + e + 8 + g);
    ushort4 v0 = *(const ushort4*)(hwS + (pk0 & 0xffffu) * SLW);
    ushort4 v1 = *(const ushort4*)(hwS + (pk1 & 0xffffu) * SLW);
    float w0 = bf2f((unsigned short)(pk0 >> 16));
    float w1 = bf2f((unsigned short)(pk1 >> 16));
    a0 += w0 * bf2f(v0.x); a1 += w0 * bf2f(v0.y);
    a2 += w0 * bf2f(v0.z); a3 += w0 * bf2f(v0.w);
    a0 += w1 * bf2f(v1.x); a1 += w1 * bf2f(v1.y);
    a2 += w1 * bf2f(v1.z); a3 += w1 * bf2f(v1.w);
  }
  for (; e < s1; e += 8) {
    int ee = e + g;
    unsigned pk = (ee < s1) ? __builtin_nontemporal_load(ewp + ee) : 0u;
    float w = bf2f((unsigned short)(pk >> 16));   // 0 for masked lanes
    ushort4 v = *(const ushort4*)(hwS + (pk & 0xffffu) * SLW);
    a0 += w * bf2f(v.x); a1 += w * bf2f(v.y);
    a2 += w * bf2f(v.z); a3 += w * bf2f(v.w);
  }
  if (g == 0) {   // self-loop (fp32 weight)
    const float di = dinv[i];
    const float w = di * di;
    ushort4 sv = *(const ushort4*)(hwS + i * SLW);
    a0 += w * bf2f(sv.x); a1 += w * bf2f(sv.y);
    a2 += w * bf2f(sv.z); a3 += w * bf2f(sv.w);
  }
  #pragma unroll
  for (int m = 8; m < 64; m <<= 1) {
    a0 += __shfl_xor(a0, m, 64);
    a1 += __shfl_xor(a1, m, 64);
    a2 += __shfl_xor(a2, m, 64);
    a3 += __shfl_xor(a3, m, 64);
  }
  if (g == 0) {
    const int c = slice * SLW + p * 4;
    const float4 bv = *(const float4*)(bias + c);
    ushort4 o;
    o.x = (unsigned short)f2bf(fmaxf(a0 + bv.x, 0.f));
    o.y = (unsigned short)f2bf(fmaxf(a1 + bv.y, 0.f));
    o.z = (unsigned short)f2bf(fmaxf(a2 + bv.z, 0.f));
    o.w = (unsigned short)f2bf(fmaxf(a3 + bv.w, 0.f));
    *(ushort4*)(out + (long)slice * ((long)NN * SLW) + i * SLW + p * 4) = o;
  }
}

// ---------------- pool + lin2 + lin3 fused v4 (slice-major bf16 input) ----------------
__global__ __launch_bounds__(256) void pool_mlp_v4(
    const unsigned short* __restrict__ h, const int* __restrict__ batch,
    const float* __restrict__ W2, const float* __restrict__ b2,
    const float* __restrict__ W3, const float* __restrict__ b3,
    float* __restrict__ out)
{
  __shared__ float part[4][DC];   // 4 KB
  __shared__ float gmean[DC];
  __shared__ float red[DL];
  const int g = blockIdx.x;
  const int t = threadIdx.x;
  const int wid = t >> 6;
  const int lane = t & 63;
  const int c0 = lane * 4;
  // slice-major: channel c0 lives at h[(c0>>5)*NN*32 + i*32 + (c0&31)]
  const unsigned short* hS = h + (long)(lane >> 3) * ((long)NN * SLW) + (lane & 7) * 4;

  int lo = 0, hi = NN;
  while (lo < hi) { int mid = (lo + hi) >> 1; if (batch[mid] < g) lo = mid + 1; else hi = mid; }
  const int start = lo;
  hi = NN;
  while (lo < hi) { int mid = (lo + hi) >> 1; if (batch[mid] < g + 1) lo = mid + 1; else hi = mid; }
  const int end = lo;

  float4 a0 = {0.f, 0.f, 0.f, 0.f}, a1 = {0.f, 0.f, 0.f, 0.f};
  int i = start + wid;
  for (; i + 4 < end; i += 8) {
    ushort4 v0 = *(const ushort4*)(hS + i * SLW);
    ushort4 v1 = *(const ushort4*)(hS + (i + 4) * SLW);
    a0.x += bf2f(v0.x); a0.y += bf2f(v0.y); a0.z += bf2f(v0.z); a0.w += bf2f(v0.w);
    a1.x += bf2f(v1.x); a1.y += bf2f(v1.y); a1.z += bf2f(v1.z); a1.w += bf2f(v1.w);
  }
  if (i < end) {
    ushort4 v0 = *(const ushort4*)(hS + i * SLW);
    a0.x += bf2f(v0.x); a0.y += bf2f(v0.y); a0.z += bf2f(v0.z); a0.w += bf2f(v0.w);
  }
  a0.x += a1.x; a0.y += a1.y; a0.z += a1.z; a0.w += a1.w;
  *(float4*)&part[wid][c0] = a0;
  __syncthreads();
  if (wid == 0) {
    const float inv = 1.0f / fmaxf((float)(end - start), 1.f);
    float4 s0 = *(const float4*)&part[0][c0];
    float4 s1 = *(const float4*)&part[1][c0];
    float4 s2 = *(const float4*)&part[2][c0];
    float4 s3 = *(const float4*)&part[3][c0];
    float4 m;
    m.x = (s0.x + s1.x + s2.x + s3.x) * inv;
    m.y = (s0.y + s1.y + s2.y + s3.y) * inv;
    m.z = (s0.z + s1.z + s2.z + s3.z) * inv;
    m.w = (s0.w + s1.w + s2.w + s3.w) * inv;
    *(float4*)&gmean[c0] = m;
  }
  __syncthreads();
  if (t < DL) {
    float acc = b2[t];
    for (int k = 0; k < DC; ++k) acc = fmaf(gmean[k], W2[k * DL + t], acc);
    red[t] = fmaxf(acc, 0.f) * W3[t];
  }
  __syncthreads();
  for (int s2 = 64; s2 > 0; s2 >>= 1) {
    if (t < s2) red[t] += red[t + s2];
    __syncthreads();
  }
  if (t == 0) out[g] = red[0] + b3[0];
}

// ---------------- launch ----------------
extern "C" void kernel_launch(void* const* d_in, const int* in_sizes, int n_in,
                              void* d_out, int out_size, void* d_ws, size_t ws_size,
                              hipStream_t stream) {
  const float* x    = (const float*)d_in[0];
  const int*   ei   = (const int*)d_in[1];
  const int*   bat  = (const int*)d_in[2];
  const float* W1   = (const float*)d_in[3];
  const float* b1   = (const float*)d_in[4];
  const float* Wc1  = (const float*)d_in[5];
  const float* bc1  = (const float*)d_in[6];
  const float* Wc2  = (const float*)d_in[7];
  const float* bc2  = (const float*)d_in[8];
  const float* W2   = (const float*)d_in[9];
  const float* b2   = (const float*)d_in[10];
  const float* W3   = (const float*)d_in[11];
  const float* b3   = (const float*)d_in[12];
  float* out = (float*)d_out;

  char* ws = (char*)d_ws;
  short* xbf    = (short*)(ws + XBF_OFF);
  short* h1bf   = (short*)(ws + H1BF_OFF);
  unsigned short* hwbf = (unsigned short*)(ws + HWBF_OFF);
  unsigned short* h2bf = (unsigned short*)(ws + H2BF_OFF);
  unsigned short* h3bf = (unsigned short*)(ws + H3BF_OFF);
  short* W1t    = (short*)(ws + W1T_OFF);
  short* Wc1t   = (short*)(ws + WC1T_OFF);
  short* Wc2t   = (short*)(ws + WC2T_OFF);
  int*   cnt    = (int*)  (ws + CNT_OFF);
  int*   fill   = (int*)  (ws + FILL_OFF);
  float* dinv   = (float*)(ws + DINV_OFF);
  int*   rowptr = (int*)  (ws + RP_OFF);
  int*   bsum   = (int*)  (ws + BSUM_OFF);
  unsigned* ewp = (unsigned*)(ws + EW_OFF);

  const int* srcE = ei;
  const int* dstE = ei + NE;

  // zero cnt + fill (adjacent) every call
  hipMemsetAsync(cnt, 0, 2 * NN * sizeof(int), stream);

  // graph structure
  count_in<<<(NE + 255) / 256, 256, 0, stream>>>(dstE, cnt);
  scan_p1<<<NB, 1024, 0, stream>>>(cnt, rowptr, bsum, dinv);
  scan_p2<<<1, 64, 0, stream>>>(bsum, rowptr);
  scan_p3<<<NB, 1024, 0, stream>>>(rowptr, bsum);
  fill_csr<<<(NE + 255) / 256, 256, 0, stream>>>(srcE, dstE, rowptr, fill, dinv, ewp);

  // fused conversions (x cvt + 3 weight transposes)
  prep<<<(1062144 + 255) / 256, 256, 0, stream>>>(x, xbf, W1, W1t, Wc1, Wc1t, Wc2, Wc2t);

  // lin1: h1 = relu(x @ W1 + b1) -> bf16 row-major
  {
    dim3 grid(DH / 128, (NN + 127) / 128);
    gemm_mfma3<1, 1, 0, 0><<<grid, 256, 0, stream>>>(xbf, W1t, b1, h1bf, NN, DIN, DH);
  }
  // conv1 matmul: hw = h1 @ Wc1 -> bf16 SLICE-MAJOR
  {
    dim3 grid(DC / 128, (NN + 127) / 128);
    gemm_mfma3<0, 0, 0, 1><<<grid, 256, 0, stream>>>(h1bf, Wc1t, nullptr, (short*)hwbf, NN, DH, DC);
  }
  // conv1 aggregate (slice-per-XCD) -> h2 slice-major
  aggregate_v7<<<8 * (NN / 4), 256, 0, stream>>>(hwbf, ewp, rowptr, dinv, bc1, h2bf);
  // conv2 matmul: hw = h2 @ Wc2 (A slice-major) -> bf16 SLICE-MAJOR
  {
    dim3 grid(DC / 128, (NN + 127) / 128);
    gemm_mfma3<0, 0, 1, 1><<<grid, 256, 0, stream>>>((const short*)h2bf, Wc2t, nullptr, (short*)hwbf, NN, DC, DC);
  }
  // conv2 aggregate -> h3 slice-major
  aggregate_v7<<<8 * (NN / 4), 256, 0, stream>>>(hwbf, ewp, rowptr, dinv, bc2, h3bf);

  // pool + lin2 + lin3
  pool_mlp_v4<<<NG, 256, 0, stream>>>(h3bf, bat, W2, b2, W3, b3, out);
}

// Round 10
// 321.038 us; speedup vs baseline: 1.6060x; 1.6060x over previous
//
#include <hip/hip_runtime.h>
#include <hip/hip_bf16.h>

#define NN 50000
#define NE 800000
#define NG 256
#define DIN 128
#define DH 512
#define DC 256   // conv channels
#define DL 128   // lin2 out
#define NB 49    // scan blocks: ceil(50000/1024)

// ---------------- workspace layout (bytes) ----------------
#define XBF_OFF   0UL            // 50000*128*2  = 12,800,000
#define H1BF_OFF  12800000UL     // 50000*512*2  = 51,200,000 -> 64,000,000
#define HWBF_OFF  64000000UL     // 50000*256*2  = 25,600,000 -> 89,600,000
#define H2BF_OFF  89600000UL     // 25,600,000 -> 115,200,000
#define H3BF_OFF  115200000UL    // 25,600,000 -> 140,800,000
#define W1T_OFF   140800000UL    // 131,072 -> 140,931,072
#define WC1T_OFF  140931072UL    // 262,144 -> 141,193,216
#define WC2T_OFF  141193216UL    // 131,072 -> 141,324,288
#define CNT_OFF   141324288UL    // 200,000
#define FILL_OFF  141524288UL    // 200,000 (must directly follow CNT: one memset)
#define DINV_OFF  141724288UL    // 200,000
#define RP_OFF    141924288UL    // 200,004
#define BSUM_OFF  142124416UL    // 256
#define EW_OFF    142124800UL    // 800000*4 = 3,200,000 -> end 145,324,800

using bf16x8 = __attribute__((ext_vector_type(8))) short;
using f32x4  = __attribute__((ext_vector_type(4))) float;

__device__ __forceinline__ short f2bf(float f) {
  unsigned u = __builtin_bit_cast(unsigned, f);
  unsigned r = u + 0x7fffu + ((u >> 16) & 1u);   // round-to-nearest-even
  return (short)(r >> 16);
}
__device__ __forceinline__ float bf2f(unsigned short u) {
  return __builtin_bit_cast(float, (unsigned)u << 16);
}

// async global->LDS, 16B per lane. LDS dest = wave-uniform base + lane*16.
__device__ __forceinline__ void gload_lds16(const void* g, void* l) {
  typedef const __attribute__((address_space(1))) unsigned gu32;
  typedef __attribute__((address_space(3))) unsigned lu32;
  __builtin_amdgcn_global_load_lds((gu32*)g, (lu32*)l, 16, 0, 0);
}

// ---------------- graph-structure kernels ----------------
__global__ void count_in(const int* __restrict__ dst, int* __restrict__ cnt) {
  int e = blockIdx.x * blockDim.x + threadIdx.x;
  if (e < NE) atomicAdd(&cnt[dst[e]], 1);
}

// ---- 3-phase exclusive scan of cnt -> rowptr; also writes dinv ----
__global__ __launch_bounds__(1024) void scan_p1(const int* __restrict__ cnt,
                                                int* __restrict__ rowptr,
                                                int* __restrict__ bsum,
                                                float* __restrict__ dinv) {
  __shared__ int wsum[16];
  const int idx = blockIdx.x * 1024 + threadIdx.x;
  const int lane = threadIdx.x & 63, wid = threadIdx.x >> 6;
  int v = (idx < NN) ? cnt[idx] : 0;
  int incl = v;
  #pragma unroll
  for (int s = 1; s < 64; s <<= 1) {
    int t = __shfl_up(incl, s, 64);
    if (lane >= s) incl += t;
  }
  if (lane == 63) wsum[wid] = incl;
  __syncthreads();
  if (wid == 0 && lane < 16) {
    int w = wsum[lane];
    int wincl = w;
    #pragma unroll
    for (int s = 1; s < 16; s <<= 1) {
      int t = __shfl_up(wincl, s, 64);
      if (lane >= s) wincl += t;
    }
    wsum[lane] = wincl - w;                 // exclusive wave offset
    if (lane == 15) bsum[blockIdx.x] = wincl;
  }
  __syncthreads();
  if (idx < NN) {
    rowptr[idx] = wsum[wid] + incl - v;
    dinv[idx] = 1.0f / sqrtf((float)(v + 1));   // +1 self-loop
  }
}

__global__ void scan_p2(int* __restrict__ bsum, int* __restrict__ rowptr) {
  const int lane = threadIdx.x;
  int v = (lane < NB) ? bsum[lane] : 0;
  int incl = v;
  #pragma unroll
  for (int s = 1; s < 64; s <<= 1) {
    int t = __shfl_up(incl, s, 64);
    if (lane >= s) incl += t;
  }
  if (lane < NB) bsum[lane] = incl - v;
  if (lane == 63) rowptr[NN] = incl;        // == NE
}

__global__ __launch_bounds__(1024) void scan_p3(int* __restrict__ rowptr,
                                                const int* __restrict__ bsum) {
  const int idx = blockIdx.x * 1024 + threadIdx.x;
  if (idx < NN && blockIdx.x > 0) rowptr[idx] += bsum[blockIdx.x];
}

// fill CSR: packed 4B edge record = src_idx (u16) | bf16(weight) << 16
__global__ void fill_csr(const int* __restrict__ src, const int* __restrict__ dst,
                         const int* __restrict__ rowptr, int* __restrict__ fill,
                         const float* __restrict__ dinv, unsigned* __restrict__ ewp) {
  int e = blockIdx.x * blockDim.x + threadIdx.x;
  if (e < NE) {
    int d = dst[e];
    int s = src[e];
    int pos = rowptr[d] + atomicAdd(&fill[d], 1);
    float w = dinv[d] * dinv[s];
    ewp[pos] = (unsigned)s | ((unsigned)(unsigned short)f2bf(w) << 16);
  }
}

// ---------------- fused prep: x->bf16 + 3 weight transposes ----------------
__global__ void prep(const float* __restrict__ x, short* __restrict__ xbf,
                     const float* __restrict__ W1, short* __restrict__ W1t,
                     const float* __restrict__ Wc1, short* __restrict__ Wc1t,
                     const float* __restrict__ Wc2, short* __restrict__ Wc2t) {
  int idx = blockIdx.x * 256 + threadIdx.x;
  if (idx < 800000) {
    const float4* p = (const float4*)x + (long)idx * 2;
    float4 a = p[0], b = p[1];
    bf16x8 o;
    o[0] = f2bf(a.x); o[1] = f2bf(a.y); o[2] = f2bf(a.z); o[3] = f2bf(a.w);
    o[4] = f2bf(b.x); o[5] = f2bf(b.y); o[6] = f2bf(b.z); o[7] = f2bf(b.w);
    *(bf16x8*)(xbf + (long)idx * 8) = o;
  } else if (idx < 865536) {
    int j = idx - 800000;             // W1t[512][128]
    int n = j >> 7, k = j & 127;
    W1t[j] = f2bf(W1[k * DH + n]);
  } else if (idx < 996608) {
    int j = idx - 865536;             // Wc1t[256][512]
    int n = j >> 9, k = j & 511;
    Wc1t[j] = f2bf(Wc1[k * DC + n]);
  } else if (idx < 1062144) {
    int j = idx - 996608;             // Wc2t[256][256]
    int n = j >> 8, k = j & 255;
    Wc2t[j] = f2bf(Wc2[k * DC + n]);
  }
}

// ---------------- bf16 MFMA GEMM v4: BK=64 (32 MFMA per barrier-pair) ----------
// 128x128 tile, 4 waves (2x2), 16x16x32 MFMA, 4x4 fragments/wave.
// Linear LDS [128][64] (32KB total) staged via global_load_lds width=16:
// each gload = 64 lanes x 16B = 1KB = 8 rows; 4 issues/wave for A, 4 for B.
// K must be a multiple of 64 (128/512/256 all ok).
template<int DO_RELU, int HAS_BIAS>
__global__ __launch_bounds__(256) void gemm_mfma4(
    const short* __restrict__ A,   // [M,K] bf16
    const short* __restrict__ Bt,  // [N,K] bf16
    const float* __restrict__ bias,
    short* __restrict__ Cout, int M, int K, int N)
{
  __shared__ __align__(16) short As[128][64];
  __shared__ __align__(16) short Bs[128][64];
  const int tid  = threadIdx.x;
  const int lane = tid & 63;
  const int wave = tid >> 6;       // 0..3
  const int wr   = wave >> 1;      // M dir
  const int wc   = wave & 1;       // N dir
  const int bm = blockIdx.y * 128;
  const int bn = blockIdx.x * 128;

  const int srow = lane >> 3;        // 0..7 within 8-row chunk
  const int scol = (lane & 7) * 8;   // short col base 0..56

  f32x4 acc[4][4];
  #pragma unroll
  for (int m = 0; m < 4; ++m)
    #pragma unroll
    for (int n = 0; n < 4; ++n)
      acc[m][n] = f32x4{0.f, 0.f, 0.f, 0.f};

  const int fr = lane & 15;          // fragment row/col
  const int kb = (lane >> 4) * 8;    // fragment k base within 32

  for (int k0 = 0; k0 < K; k0 += 64) {
    #pragma unroll
    for (int j = 0; j < 4; ++j) {
      const int r = wave * 32 + j * 8;   // rows [wave*32, wave*32+32)
      gload_lds16(A  + (long)(bm + r + srow) * K + k0 + scol, &As[r][0]);
      gload_lds16(Bt + (long)(bn + r + srow) * K + k0 + scol, &Bs[r][0]);
    }
    __syncthreads();   // drains vmcnt -> LDS writes visible
    #pragma unroll
    for (int kk = 0; kk < 2; ++kk) {
      bf16x8 af[4], bfr[4];
      #pragma unroll
      for (int m = 0; m < 4; ++m)
        af[m] = *(const bf16x8*)&As[wr * 64 + m * 16 + fr][kk * 32 + kb];
      #pragma unroll
      for (int n = 0; n < 4; ++n)
        bfr[n] = *(const bf16x8*)&Bs[wc * 64 + n * 16 + fr][kk * 32 + kb];
      #pragma unroll
      for (int m = 0; m < 4; ++m)
        #pragma unroll
        for (int n = 0; n < 4; ++n)
          acc[m][n] = __builtin_amdgcn_mfma_f32_16x16x32_bf16(af[m], bfr[n], acc[m][n], 0, 0, 0);
    }
    __syncthreads();
  }

  const int cr4 = (lane >> 4) * 4;
  const int cc  = lane & 15;
  #pragma unroll
  for (int m = 0; m < 4; ++m) {
    #pragma unroll
    for (int r = 0; r < 4; ++r) {
      int gm = bm + wr * 64 + m * 16 + cr4 + r;
      if (gm >= M) continue;
      #pragma unroll
      for (int n = 0; n < 4; ++n) {
        int gn = bn + wc * 64 + n * 16 + cc;
        float v = acc[m][n][r];
        if (HAS_BIAS) v += bias[gn];
        if (DO_RELU) v = fmaxf(v, 0.f);
        Cout[(long)gm * N + gn] = f2bf(v);
      }
    }
  }
}

// ---------------- GCN aggregation v6 (row-major, packed 4B edge records) ----
// 1 wave per node, 4 channels per lane (ushort4, 8B) -> one full 512B row per
// wave-instruction. Edge loop unrolled 8/4/1; records nt-loaded.
__global__ __launch_bounds__(256) void aggregate_v6(
    const unsigned short* __restrict__ hw, const unsigned* __restrict__ ewp,
    const int* __restrict__ rowptr, const float* __restrict__ dinv,
    const float* __restrict__ bias, unsigned short* __restrict__ out)
{
  const int wid  = threadIdx.x >> 6;
  const int lane = threadIdx.x & 63;
  const int i = blockIdx.x * 4 + wid;
  if (i >= NN) return;
  const int c0 = lane * 4;
  const float di = dinv[i];

  ushort4 sv = *(const ushort4*)(hw + (long)i * DC + c0);
  const float dii = di * di;
  float acc0 = dii * bf2f(sv.x);
  float acc1 = dii * bf2f(sv.y);
  float acc2 = dii * bf2f(sv.z);
  float acc3 = dii * bf2f(sv.w);

  const int s0 = rowptr[i], s1 = rowptr[i + 1];
  int e = s0;
  for (; e + 8 <= s1; e += 8) {
    unsigned pk[8]; ushort4 vv[8];
    #pragma unroll
    for (int j = 0; j < 8; ++j) pk[j] = __builtin_nontemporal_load(ewp + e + j);
    #pragma unroll
    for (int j = 0; j < 8; ++j)
      vv[j] = *(const ushort4*)(hw + (long)(pk[j] & 0xffffu) * DC + c0);
    #pragma unroll
    for (int j = 0; j < 8; ++j) {
      float w = bf2f((unsigned short)(pk[j] >> 16));
      acc0 += w * bf2f(vv[j].x);
      acc1 += w * bf2f(vv[j].y);
      acc2 += w * bf2f(vv[j].z);
      acc3 += w * bf2f(vv[j].w);
    }
  }
  for (; e + 4 <= s1; e += 4) {
    unsigned pk[4]; ushort4 vv[4];
    #pragma unroll
    for (int j = 0; j < 4; ++j) pk[j] = __builtin_nontemporal_load(ewp + e + j);
    #pragma unroll
    for (int j = 0; j < 4; ++j)
      vv[j] = *(const ushort4*)(hw + (long)(pk[j] & 0xffffu) * DC + c0);
    #pragma unroll
    for (int j = 0; j < 4; ++j) {
      float w = bf2f((unsigned short)(pk[j] >> 16));
      acc0 += w * bf2f(vv[j].x);
      acc1 += w * bf2f(vv[j].y);
      acc2 += w * bf2f(vv[j].z);
      acc3 += w * bf2f(vv[j].w);
    }
  }
  for (; e < s1; ++e) {
    unsigned pk = __builtin_nontemporal_load(ewp + e);
    float w = bf2f((unsigned short)(pk >> 16));
    ushort4 v = *(const ushort4*)(hw + (long)(pk & 0xffffu) * DC + c0);
    acc0 += w * bf2f(v.x);
    acc1 += w * bf2f(v.y);
    acc2 += w * bf2f(v.z);
    acc3 += w * bf2f(v.w);
  }
  const float4 bv = *(const float4*)(bias + c0);
  ushort4 o;
  o.x = (unsigned short)f2bf(fmaxf(acc0 + bv.x, 0.f));
  o.y = (unsigned short)f2bf(fmaxf(acc1 + bv.y, 0.f));
  o.z = (unsigned short)f2bf(fmaxf(acc2 + bv.z, 0.f));
  o.w = (unsigned short)f2bf(fmaxf(acc3 + bv.w, 0.f));
  *(ushort4*)(out + (long)i * DC + c0) = o;
}

// ---------------- pool + lin2 + lin3 fused v3 (bf16 input) ----------------
__global__ __launch_bounds__(256) void pool_mlp_v3(
    const unsigned short* __restrict__ h, const int* __restrict__ batch,
    const float* __restrict__ W2, const float* __restrict__ b2,
    const float* __restrict__ W3, const float* __restrict__ b3,
    float* __restrict__ out)
{
  __shared__ float part[4][DC];   // 4 KB
  __shared__ float gmean[DC];
  __shared__ float red[DL];
  const int g = blockIdx.x;
  const int t = threadIdx.x;
  const int wid = t >> 6;
  const int lane = t & 63;
  const int c0 = lane * 4;

  int lo = 0, hi = NN;
  while (lo < hi) { int mid = (lo + hi) >> 1; if (batch[mid] < g) lo = mid + 1; else hi = mid; }
  const int start = lo;
  hi = NN;
  while (lo < hi) { int mid = (lo + hi) >> 1; if (batch[mid] < g + 1) lo = mid + 1; else hi = mid; }
  const int end = lo;

  float4 a0 = {0.f, 0.f, 0.f, 0.f}, a1 = {0.f, 0.f, 0.f, 0.f};
  int i = start + wid;
  for (; i + 4 < end; i += 8) {
    ushort4 v0 = *(const ushort4*)(h + (long)i * DC + c0);
    ushort4 v1 = *(const ushort4*)(h + (long)(i + 4) * DC + c0);
    a0.x += bf2f(v0.x); a0.y += bf2f(v0.y); a0.z += bf2f(v0.z); a0.w += bf2f(v0.w);
    a1.x += bf2f(v1.x); a1.y += bf2f(v1.y); a1.z += bf2f(v1.z); a1.w += bf2f(v1.w);
  }
  if (i < end) {
    ushort4 v0 = *(const ushort4*)(h + (long)i * DC + c0);
    a0.x += bf2f(v0.x); a0.y += bf2f(v0.y); a0.z += bf2f(v0.z); a0.w += bf2f(v0.w);
  }
  a0.x += a1.x; a0.y += a1.y; a0.z += a1.z; a0.w += a1.w;
  *(float4*)&part[wid][c0] = a0;
  __syncthreads();
  if (wid == 0) {
    const float inv = 1.0f / fmaxf((float)(end - start), 1.f);
    float4 s0 = *(const float4*)&part[0][c0];
    float4 s1 = *(const float4*)&part[1][c0];
    float4 s2 = *(const float4*)&part[2][c0];
    float4 s3 = *(const float4*)&part[3][c0];
    float4 m;
    m.x = (s0.x + s1.x + s2.x + s3.x) * inv;
    m.y = (s0.y + s1.y + s2.y + s3.y) * inv;
    m.z = (s0.z + s1.z + s2.z + s3.z) * inv;
    m.w = (s0.w + s1.w + s2.w + s3.w) * inv;
    *(float4*)&gmean[c0] = m;
  }
  __syncthreads();
  if (t < DL) {
    float acc = b2[t];
    for (int k = 0; k < DC; ++k) acc = fmaf(gmean[k], W2[k * DL + t], acc);
    red[t] = fmaxf(acc, 0.f) * W3[t];
  }
  __syncthreads();
  for (int s2 = 64; s2 > 0; s2 >>= 1) {
    if (t < s2) red[t] += red[t + s2];
    __syncthreads();
  }
  if (t == 0) out[g] = red[0] + b3[0];
}

// ---------------- launch ----------------
extern "C" void kernel_launch(void* const* d_in, const int* in_sizes, int n_in,
                              void* d_out, int out_size, void* d_ws, size_t ws_size,
                              hipStream_t stream) {
  const float* x    = (const float*)d_in[0];
  const int*   ei   = (const int*)d_in[1];
  const int*   bat  = (const int*)d_in[2];
  const float* W1   = (const float*)d_in[3];
  const float* b1   = (const float*)d_in[4];
  const float* Wc1  = (const float*)d_in[5];
  const float* bc1  = (const float*)d_in[6];
  const float* Wc2  = (const float*)d_in[7];
  const float* bc2  = (const float*)d_in[8];
  const float* W2   = (const float*)d_in[9];
  const float* b2   = (const float*)d_in[10];
  const float* W3   = (const float*)d_in[11];
  const float* b3   = (const float*)d_in[12];
  float* out = (float*)d_out;

  char* ws = (char*)d_ws;
  short* xbf    = (short*)(ws + XBF_OFF);
  short* h1bf   = (short*)(ws + H1BF_OFF);
  unsigned short* hwbf = (unsigned short*)(ws + HWBF_OFF);
  unsigned short* h2bf = (unsigned short*)(ws + H2BF_OFF);
  unsigned short* h3bf = (unsigned short*)(ws + H3BF_OFF);
  short* W1t    = (short*)(ws + W1T_OFF);
  short* Wc1t   = (short*)(ws + WC1T_OFF);
  short* Wc2t   = (short*)(ws + WC2T_OFF);
  int*   cnt    = (int*)  (ws + CNT_OFF);
  int*   fill   = (int*)  (ws + FILL_OFF);
  float* dinv   = (float*)(ws + DINV_OFF);
  int*   rowptr = (int*)  (ws + RP_OFF);
  int*   bsum   = (int*)  (ws + BSUM_OFF);
  unsigned* ewp = (unsigned*)(ws + EW_OFF);

  const int* srcE = ei;
  const int* dstE = ei + NE;

  // zero cnt + fill (adjacent) every call
  hipMemsetAsync(cnt, 0, 2 * NN * sizeof(int), stream);

  // graph structure
  count_in<<<(NE + 255) / 256, 256, 0, stream>>>(dstE, cnt);
  scan_p1<<<NB, 1024, 0, stream>>>(cnt, rowptr, bsum, dinv);
  scan_p2<<<1, 64, 0, stream>>>(bsum, rowptr);
  scan_p3<<<NB, 1024, 0, stream>>>(rowptr, bsum);
  fill_csr<<<(NE + 255) / 256, 256, 0, stream>>>(srcE, dstE, rowptr, fill, dinv, ewp);

  // fused conversions (x cvt + 3 weight transposes)
  prep<<<(1062144 + 255) / 256, 256, 0, stream>>>(x, xbf, W1, W1t, Wc1, Wc1t, Wc2, Wc2t);

  // lin1: h1 = relu(x @ W1 + b1) -> bf16
  {
    dim3 grid(DH / 128, (NN + 127) / 128);
    gemm_mfma4<1, 1><<<grid, 256, 0, stream>>>(xbf, W1t, b1, h1bf, NN, DIN, DH);
  }
  // conv1 matmul: hw = h1 @ Wc1 -> bf16
  {
    dim3 grid(DC / 128, (NN + 127) / 128);
    gemm_mfma4<0, 0><<<grid, 256, 0, stream>>>(h1bf, Wc1t, nullptr, (short*)hwbf, NN, DH, DC);
  }
  // conv1 aggregate -> h2 (bias + relu) -> bf16
  aggregate_v6<<<(NN + 3) / 4, 256, 0, stream>>>(hwbf, ewp, rowptr, dinv, bc1, h2bf);
  // conv2 matmul: hw = h2 @ Wc2 -> bf16
  {
    dim3 grid(DC / 128, (NN + 127) / 128);
    gemm_mfma4<0, 0><<<grid, 256, 0, stream>>>((const short*)h2bf, Wc2t, nullptr, (short*)hwbf, NN, DC, DC);
  }
  // conv2 aggregate -> h3 (bias + relu) -> bf16
  aggregate_v6<<<(NN + 3) / 4, 256, 0, stream>>>(hwbf, ewp, rowptr, dinv, bc2, h3bf);

  // pool + lin2 + lin3
  pool_mlp_v3<<<NG, 256, 0, stream>>>(h3bf, bat, W2, b2, W3, b3, out);
}